// Round 17
// baseline (1480.392 us; speedup 1.0000x reference)
//
#include <hip/hip_runtime.h>
#include <stdint.h>
#include <math.h>

// PendulumHJBLoss: 3 MLP passes (2->128->128->2, tanh) over N=524288 + losses.
// R17 = R16 with the exec-mask shfl bug fixed: the recon-loss shfls
// (Lp0/Lq0 from p0e/q0e) now execute with ALL lanes active (they were inside
// the l15<4 branch, whose source lanes were inactive for quad>=1).
// Structure: layer-1 computed directly in A-frag layout (lane owns elem l15,
// dims 32s+8*quad+j; W1/b1 via LDS float4 broadcasts), UNPAIRED MFMA streams
// (A[4]=16 live regs), LDS = 64KB B-tables + ~6KB consts = ~72KB ->
// 2 blocks/CU -> 32 waves/CU at the allocator's 64-VGPR choice. Grid 512.
// tanh-scale folding kept. Symp rows exact fp32 via shfl broadcast.

constexpr float EPS_FD = 1e-4f;
constexpr float K2LOG2E = 2.8853900817779268f;   // 2*log2(e)
constexpr int NBLK = 512;          // 2 blocks/CU, 16 waves each

typedef float f32x4 __attribute__((ext_vector_type(4)));
typedef short s16x8 __attribute__((ext_vector_type(8)));

// tanh with pre-scaled input: expects x_pre = 2*log2(e) * x
__device__ __forceinline__ float tanh_pre(float x) {
  float e = __builtin_amdgcn_exp2f(x);
  return 1.0f - 2.0f * __builtin_amdgcn_rcpf(e + 1.0f);
}
__device__ __forceinline__ float cos_fast(float x) {
  return __builtin_amdgcn_cosf(x * 0.15915494309189535f);
}
__device__ __forceinline__ unsigned bf16rne(float f) {
  union { float f; unsigned u; } v; v.f = f;
  return (v.u + 0x7FFFu + ((v.u >> 16) & 1u)) >> 16;
}
__device__ __forceinline__ unsigned pack2rne(float a, float b) {
  return bf16rne(a) | (bf16rne(b) << 16);
}
// two fp32 -> packed bf16 pair (round-half-up) with one v_perm
__device__ __forceinline__ unsigned packbf(float lo, float hi) {
  union { float f; unsigned u; } a, b; a.f = lo; b.f = hi;
  return __builtin_amdgcn_perm(b.u + 0x8000u, a.u + 0x8000u, 0x07060302u);
}

// ---------------------------------------------------------------------------
// Direct layer-1 (single stream): lane computes acts for its element (pe,qe)
// at dims k = 32s + 8*quad + j, j=0..7 -> A[s]. W slices = LDS float4
// broadcasts (pre-scaled by K2LOG2E).
// ---------------------------------------------------------------------------
__device__ __forceinline__ void l1_direct(
    float pe, float qe,
    const float* w0s, const float* w1s, const float* bs, int quad,
    s16x8 (&A)[4])
{
#pragma unroll
  for (int s = 0; s < 4; s++) {
    int kb = 32 * s + 8 * quad;
    float4 w0a = *(const float4*)&w0s[kb], w0b = *(const float4*)&w0s[kb + 4];
    float4 w1a = *(const float4*)&w1s[kb], w1b = *(const float4*)&w1s[kb + 4];
    float4 ba  = *(const float4*)&bs[kb],  bb  = *(const float4*)&bs[kb + 4];
    float xl, xh;
    unsigned u0, u1, u2, u3;
    xl = tanh_pre(fmaf(pe, w0a.x, fmaf(qe, w1a.x, ba.x)));
    xh = tanh_pre(fmaf(pe, w0a.y, fmaf(qe, w1a.y, ba.y)));
    u0 = packbf(xl, xh);
    xl = tanh_pre(fmaf(pe, w0a.z, fmaf(qe, w1a.z, ba.z)));
    xh = tanh_pre(fmaf(pe, w0a.w, fmaf(qe, w1a.w, ba.w)));
    u1 = packbf(xl, xh);
    xl = tanh_pre(fmaf(pe, w0b.x, fmaf(qe, w1b.x, bb.x)));
    xh = tanh_pre(fmaf(pe, w0b.y, fmaf(qe, w1b.y, bb.y)));
    u2 = packbf(xl, xh);
    xl = tanh_pre(fmaf(pe, w0b.z, fmaf(qe, w1b.z, bb.z)));
    xh = tanh_pre(fmaf(pe, w0b.w, fmaf(qe, w1b.w, bb.w)));
    u3 = packbf(xl, xh);
    uint4 v = {u0, u1, u2, u3};
    A[s] = *reinterpret_cast<s16x8*>(&v);
  }
}

// ---------------------------------------------------------------------------
// MFMA + epilogue, single stream. B-frags from LDS; epi = K*b2 | W3P | W3Q.
// Output valid on lanes l15<4: element = base + quad*4 + l15.
// ---------------------------------------------------------------------------
__device__ __forceinline__ void mfma_epi(
    const s16x8 (&A)[4], const uint4* Bf, const float* epi, int lane, int l15,
    float& vP, float& vQ)
{
  float sP[4] = {0,0,0,0}, sQ[4] = {0,0,0,0};
#pragma unroll
  for (int t = 0; t < 8; t++) {
    float b2v = epi[16 * t + l15];
    f32x4 acc = {b2v, b2v, b2v, b2v};
#pragma unroll
    for (int s = 0; s < 4; s++) {
      uint4 bu = Bf[(s * 8 + t) * 64 + lane];
      s16x8 Bv = *reinterpret_cast<s16x8*>(&bu);
      acc = __builtin_amdgcn_mfma_f32_16x16x32_bf16(A[s], Bv, acc, 0, 0, 0);
    }
    float w3Pv = epi[128 + 16 * t + l15];
    float w3Qv = epi[256 + 16 * t + l15];
#pragma unroll
    for (int r = 0; r < 4; r++) {
      float h = tanh_pre(acc[r]);
      sP[r] = fmaf(h, w3Pv, sP[r]);
      sQ[r] = fmaf(h, w3Qv, sQ[r]);
    }
  }
#pragma unroll
  for (int m = 1; m < 16; m <<= 1) {
#pragma unroll
    for (int r = 0; r < 4; r++) {
      sP[r] += __shfl_xor(sP[r], m, 64);
      sQ[r] += __shfl_xor(sQ[r], m, 64);
    }
  }
  vP = (l15 == 0) ? sP[0] : (l15 == 1) ? sP[1] : (l15 == 2) ? sP[2] : sP[3];
  vQ = (l15 == 0) ? sQ[0] : (l15 == 1) ? sQ[1] : (l15 == 2) ? sQ[2] : sQ[3];
}

// ---------------------------------------------------------------------------
// Main persistent kernel: ~72KB LDS -> 2 blocks/CU at 64 VGPR -> 32 waves/CU.
// ---------------------------------------------------------------------------
__global__ __launch_bounds__(1024, 1) void mlp_main(
    const float* __restrict__ p0, const float* __restrict__ q0,
    const float* __restrict__ p1, const float* __restrict__ q1,
    const float* __restrict__ eW1, const float* __restrict__ eb1,
    const float* __restrict__ eW2, const float* __restrict__ eb2,
    const float* __restrict__ eW3, const float* __restrict__ eb3,
    const float* __restrict__ dW1, const float* __restrict__ db1,
    const float* __restrict__ dW2, const float* __restrict__ db2,
    const float* __restrict__ dW3, const float* __restrict__ db3,
    const float* __restrict__ omega, const float* __restrict__ Pt,
    const float* __restrict__ Qt, const float* __restrict__ dtp,
    float* __restrict__ acc5, unsigned* __restrict__ counter,
    float* __restrict__ PQ, float* __restrict__ out, int n)
{
  __shared__ uint4 BfE[2048];               // 32 KB enc B-frags (pre-scaled)
  __shared__ uint4 BfD[2048];               // 32 KB dec B-frags (pre-scaled)
  __shared__ __align__(16) float sEw0[128], sEw1[128], sEb[128];
  __shared__ __align__(16) float sDw0[128], sDw1[128], sDb[128];
  __shared__ float encEpi[384];             // enc K*b2 | W3P | W3Q
  __shared__ float decEpi[384];             // dec K*b2 | W3P | W3Q
  __shared__ float red[16][5];
  __shared__ unsigned lastflag;

  int tid = threadIdx.x;
  // self-swizzle both W2s (scaled) into LDS B-frags:
  // frag f=s*8+t; lane L holds B[k=32s+(L>>4)*8+j][col=16t+(L&15)]
#pragma unroll
  for (int it = 0; it < 8; it++) {
    int id = tid + it * 1024;               // u32 entry 0..8191
    int jj = id & 3, ln = (id >> 2) & 63, f = id >> 8;
    int s = f >> 3, t = f & 7;
    int k   = 32 * s + 8 * (ln >> 4) + 2 * jj;
    int col = 16 * t + (ln & 15);
    ((unsigned*)BfE)[id] = pack2rne(eW2[k * 128 + col] * K2LOG2E,
                                    eW2[(k + 1) * 128 + col] * K2LOG2E);
    ((unsigned*)BfD)[id] = pack2rne(dW2[k * 128 + col] * K2LOG2E,
                                    dW2[(k + 1) * 128 + col] * K2LOG2E);
  }
  if (tid < 128) {
    sEw0[tid] = eW1[tid] * K2LOG2E;
    sEw1[tid] = eW1[128 + tid] * K2LOG2E;
    sEb[tid]  = eb1[tid] * K2LOG2E;
    sDw0[tid] = dW1[tid] * K2LOG2E;
    sDw1[tid] = dW1[128 + tid] * K2LOG2E;
    sDb[tid]  = db1[tid] * K2LOG2E;
  } else if (tid < 256) {
    int u = tid - 128;
    encEpi[u]       = eb2[u] * K2LOG2E;
    encEpi[128 + u] = eW3[2 * u];
    encEpi[256 + u] = eW3[2 * u + 1];
  } else if (tid < 384) {
    int u = tid - 256;
    decEpi[u]       = db2[u] * K2LOG2E;
    decEpi[128 + u] = dW3[2 * u];
    decEpi[256 + u] = dW3[2 * u + 1];
  }

  int wave = tid >> 6, lane = tid & 63;
  int quad = lane >> 4, l15 = lane & 15;

  float eb3P = eb3[0], eb3Q = eb3[1];
  float db3P = db3[0], db3Q = db3[1];
  float dt = dtp[0];
  float s0 = 0.f, s1 = 0.f, s2 = 0.f, s3 = 0.f, s4 = 0.f;
  __syncthreads();   // LDS staging done; the only block barrier before tail

  int nwaves = gridDim.x * 16;
  int gwave  = blockIdx.x * 16 + wave;
  int ntiles = (n + 15) >> 4;

  // ---- fused exact-fp32 symplectic rows (shfl broadcast, raw weights) ----
  if (gwave < 128) {
    int r = gwave;
    int m = r & 31, c = r >> 5;           // c: 0=p+e 1=p-e 2=q+e 3=q-e
    float p = p0[m], q = q0[m];
    p += (c == 0) ? EPS_FD : (c == 1) ? -EPS_FD : 0.f;
    q += (c == 2) ? EPS_FD : (c == 3) ? -EPS_FD : 0.f;
    int t0 = 2 * lane, t1 = 2 * lane + 1;
    float h0  = tanhf(fmaf(p, eW1[t0], fmaf(q, eW1[128 + t0], eb1[t0])));
    float h1v = tanhf(fmaf(p, eW1[t1], fmaf(q, eW1[128 + t1], eb1[t1])));
    float a0 = eb2[t0], a1 = eb2[t1];
#pragma unroll 16
    for (int k = 0; k < 128; k++) {
      float hk = __shfl((k & 1) ? h1v : h0, k >> 1, 64);  // broadcast h1[k]
      a0 = fmaf(hk, eW2[k * 128 + t0], a0);
      a1 = fmaf(hk, eW2[k * 128 + t1], a1);
    }
    float g0 = tanhf(a0), g1 = tanhf(a1);
    float cP = fmaf(g0, eW3[2 * t0],     g1 * eW3[2 * t1]);
    float cQ = fmaf(g0, eW3[2 * t0 + 1], g1 * eW3[2 * t1 + 1]);
#pragma unroll
    for (int mm = 1; mm < 64; mm <<= 1) {
      cP += __shfl_xor(cP, mm, 64);
      cQ += __shfl_xor(cQ, mm, 64);
    }
    if (lane == 0) {
      atomicExch(&PQ[2 * r],     cP + eb3P);   // device-scope publish
      atomicExch(&PQ[2 * r + 1], cQ + eb3Q);
    }
  }

  int decsrc  = 16 * (l15 >> 2) + (l15 & 3);  // owner lane of element l15
  int losssrc = 4 * quad + (l15 & 3);         // lane (0..15) holding elem o16

  for (int tile = gwave; tile < ntiles; tile += nwaves) {
    int base = tile * 16;
    int e = base + l15; if (e >= n) e = n - 1;
    float p0e = p0[e], q0e = q0[e];
    float p1e = p1[e], q1e = q1[e];
    // hoisted loss loads (arrays not already in registers)
    int o = base + quad * 4 + l15;                 // valid where l15<4
    int o16 = base + quad * 4 + (l15 & 3);
    if (o16 >= n) o16 = n - 1;
    float Lom = omega[o16], LPt = Pt[o16], LQt = Qt[o16];
    // recon operands via shfl -- ALL lanes active here (fix for R16 bug)
    float Lp0 = __shfl(p0e, losssrc, 64);          // p0[o16]
    float Lq0 = __shfl(q0e, losssrc, 64);          // q0[o16]

    s16x8 A[4];
    float P0v, Q0v, P1v, Q1v, RPv, RQv;
    // enc(p0,q0)
    l1_direct(p0e, q0e, sEw0, sEw1, sEb, quad, A);
    mfma_epi(A, BfE, encEpi, lane, l15, P0v, Q0v);
    P0v += eb3P; Q0v += eb3Q;
    // enc(p1,q1)
    l1_direct(p1e, q1e, sEw0, sEw1, sEb, quad, A);
    mfma_epi(A, BfE, encEpi, lane, l15, P1v, Q1v);
    P1v += eb3P; Q1v += eb3Q;
    // dec: element l15's (P0,Q0) via 2 shfls (all lanes active)
    float dpe = __shfl(P0v, decsrc, 64);
    float dqe = __shfl(Q0v, decsrc, 64);
    l1_direct(dpe, dqe, sDw0, sDw1, sDb, quad, A);
    mfma_epi(A, BfD, decEpi, lane, l15, RPv, RQv);
    RPv += db3P; RQv += db3Q;

    if (l15 < 4 && o < n) {
      float dp = Lp0 - RPv, dq = Lq0 - RQv;
      s0 += dp * dp + dq * dq;                       // recon
      float d1 = P0v - P1v; s1 += d1 * d1;           // conservation
      s2 += 1.0f - cos_fast(Q1v - Q0v - Lom * dt);   // evolution
      float g = P0v - LPt; s3 += g * g;              // gauge P
      s4 += 1.0f - cos_fast(Q0v - LQt);              // gauge Q
    }
  }

  // block reduction -> global atomics -> ticket -> last block finalizes
#pragma unroll
  for (int m = 1; m < 64; m <<= 1) {
    s0 += __shfl_xor(s0, m, 64);
    s1 += __shfl_xor(s1, m, 64);
    s2 += __shfl_xor(s2, m, 64);
    s3 += __shfl_xor(s3, m, 64);
    s4 += __shfl_xor(s4, m, 64);
  }
  if (lane == 0) {
    red[wave][0] = s0; red[wave][1] = s1; red[wave][2] = s2;
    red[wave][3] = s3; red[wave][4] = s4;
  }
  __syncthreads();
  if (tid == 0) {
#pragma unroll
    for (int i = 0; i < 5; i++) {
      float v = 0.f;
#pragma unroll
      for (int w = 0; w < 16; w++) v += red[w][i];
      atomicAdd(&acc5[i], v);
    }
    __threadfence();
    unsigned prev = atomicAdd(counter, 1u);
    lastflag = (prev == gridDim.x - 1) ? 1u : 0u;
  }
  __syncthreads();
  if (lastflag) {
    __threadfence();
    if (tid < 64) {
      float v = 0.f;
      if (tid < 32) {
        // PQ read through device-scope atomics (cross-XCD safe)
        float Ppp = atomicAdd(&PQ[2 * tid], 0.f);
        float Qpp = atomicAdd(&PQ[2 * tid + 1], 0.f);
        float Ppm = atomicAdd(&PQ[2 * (32 + tid)], 0.f);
        float Qpm = atomicAdd(&PQ[2 * (32 + tid) + 1], 0.f);
        float Pqp = atomicAdd(&PQ[2 * (64 + tid)], 0.f);
        float Qqp = atomicAdd(&PQ[2 * (64 + tid) + 1], 0.f);
        float Pqm = atomicAdd(&PQ[2 * (96 + tid)], 0.f);
        float Qqm = atomicAdd(&PQ[2 * (96 + tid) + 1], 0.f);
        float inv2e = 1.0f / (2.0f * EPS_FD);
        float dPdp = (Ppp - Ppm) * inv2e, dPdq = (Pqp - Pqm) * inv2e;
        float dQdp = (Qpp - Qpm) * inv2e, dQdq = (Qqp - Qqm) * inv2e;
        float pb = dPdq * dQdp - dPdp * dQdq;
        float d = fabsf(pb) - 1.0f;
        v = d * d;
      }
#pragma unroll
      for (int m = 1; m < 64; m <<= 1) v += __shfl_xor(v, m, 64);
      if (tid == 0) {
        float inv_n = 1.0f / (float)n;
        float recon = atomicAdd(&acc5[0], 0.f) * inv_n;
        float cons  = atomicAdd(&acc5[1], 0.f) * inv_n;
        float evo   = atomicAdd(&acc5[2], 0.f) * inv_n;
        float gauge = (atomicAdd(&acc5[3], 0.f) + atomicAdd(&acc5[4], 0.f)) * inv_n;
        float symp  = v * (1.0f / 32.0f);
        float total = recon + 10.0f * cons + 5.0f * evo + 0.1f * symp + 5.0f * gauge;
        out[0] = total; out[1] = recon; out[2] = cons;
        out[3] = evo;   out[4] = symp;  out[5] = gauge;
      }
    }
  }
}

extern "C" void kernel_launch(void* const* d_in, const int* in_sizes, int n_in,
                              void* d_out, int out_size, void* d_ws, size_t ws_size,
                              hipStream_t stream)
{
  const float* p0    = (const float*)d_in[0];
  const float* q0    = (const float*)d_in[1];
  const float* p1    = (const float*)d_in[2];
  const float* q1    = (const float*)d_in[3];
  const float* omega = (const float*)d_in[4];
  const float* dtp   = (const float*)d_in[5];
  const float* Pt    = (const float*)d_in[6];
  const float* Qt    = (const float*)d_in[7];
  const float* encW1 = (const float*)d_in[8];
  const float* encb1 = (const float*)d_in[9];
  const float* encW2 = (const float*)d_in[10];
  const float* encb2 = (const float*)d_in[11];
  const float* encW3 = (const float*)d_in[12];
  const float* encb3 = (const float*)d_in[13];
  const float* decW1 = (const float*)d_in[14];
  const float* decb1 = (const float*)d_in[15];
  const float* decW2 = (const float*)d_in[16];
  const float* decb2 = (const float*)d_in[17];
  const float* decW3 = (const float*)d_in[18];
  const float* decb3 = (const float*)d_in[19];

  int n = in_sizes[0];
  float* acc5 = (float*)d_ws;                  // 5 loss accumulators
  unsigned* counter = (unsigned*)(acc5 + 8);   // ticket
  float* PQ = (float*)(acc5 + 16);             // 256 floats (symp encodes)

  hipMemsetAsync(acc5, 0, 64, stream);         // acc5 + counter

  mlp_main<<<NBLK, 1024, 0, stream>>>(
      p0, q0, p1, q1,
      encW1, encb1, encW2, encb2, encW3, encb3,
      decW1, decb1, decW2, decb2, decW3, decb3,
      omega, Pt, Qt, dtp, acc5, counter, PQ, (float*)d_out, n);
}

// Round 18
// 268.128 us; speedup vs baseline: 5.5212x; 5.5212x over previous
//
#include <hip/hip_runtime.h>
#include <stdint.h>
#include <math.h>

// PendulumHJBLoss: 3 MLP passes (2->128->128->2, tanh) over N=524288 + losses.
// R18 = R14 verbatim (measured best: 270.1us total, main 195us, no spill).
// Structure: enc passes paired over one LDS B-read stream, A-frags staged
// through wave-private LDS (REQUIRED: allocator pins 64 VGPR for 1024-thr
// blocks -- all 5 direct-layout variants R10-R17 spilled GBs to scratch),
// tanh-scale folding (W1/b1/W2/b2 pre-scaled by 2*log2e), fused exact-fp32
// symplectic rows on waves 0..127, ticket-elected finalize.
// Known bounds: main kernel is dependency-stall bound at 16 waves/CU
// (VALUBusy~60%); more waves can't fit (139KB LDS) without spilling.

constexpr float EPS_FD = 1e-4f;
constexpr float K2LOG2E = 2.8853900817779268f;   // 2*log2(e)
constexpr int NBLK = 256;          // 1 block/CU, 16 waves each

typedef float f32x4 __attribute__((ext_vector_type(4)));
typedef short s16x8 __attribute__((ext_vector_type(8)));

// tanh with pre-scaled input: expects x_pre = 2*log2(e) * x
__device__ __forceinline__ float tanh_pre(float x) {
  float e = __builtin_amdgcn_exp2f(x);
  return 1.0f - 2.0f * __builtin_amdgcn_rcpf(e + 1.0f);
}
__device__ __forceinline__ float cos_fast(float x) {
  return __builtin_amdgcn_cosf(x * 0.15915494309189535f);
}
__device__ __forceinline__ unsigned bf16rne(float f) {
  union { float f; unsigned u; } v; v.f = f;
  return (v.u + 0x7FFFu + ((v.u >> 16) & 1u)) >> 16;
}
__device__ __forceinline__ unsigned pack2rne(float a, float b) {
  return bf16rne(a) | (bf16rne(b) << 16);
}
// two fp32 -> packed bf16 pair (round-half-up) with one v_perm
__device__ __forceinline__ unsigned packbf(float lo, float hi) {
  union { float f; unsigned u; } a, b; a.f = lo; b.f = hi;
  return __builtin_amdgcn_perm(b.u + 0x8000u, a.u + 0x8000u, 0x07060302u);
}

// ---------------------------------------------------------------------------
// layer-1 for one 16-elem tile -> A-frags in regs (via wave-private LDS).
// Weights/bias pre-scaled by K2LOG2E; tanh_pre needs no input mul.
// SCAT: input owner lanes are 16*(ee>>2)+(ee&3) instead of 0..15.
// ---------------------------------------------------------------------------
template<bool SCAT>
__device__ __forceinline__ void layer1_frags(
    float pe, float qe, unsigned* hrow,
    float w100, float w101, float w110, float w111, float b10, float b11,
    int lane, int quad, int l15, s16x8 (&A)[4])
{
#pragma unroll
  for (int ee = 0; ee < 16; ee++) {
    int src = SCAT ? (16 * (ee >> 2) + (ee & 3)) : ee;
    float p = __shfl(pe, src, 64);
    float q = __shfl(qe, src, 64);
    float a0 = tanh_pre(fmaf(p, w100, fmaf(q, w110, b10)));
    float a1 = tanh_pre(fmaf(p, w101, fmaf(q, w111, b11)));
    hrow[ee * 68 + lane] = packbf(a0, a1);
  }
  __builtin_amdgcn_wave_barrier();   // same-wave LDS ops are in-order
#pragma unroll
  for (int s = 0; s < 4; s++) {
    uint4 u = *reinterpret_cast<const uint4*>(&hrow[l15 * 68 + 16 * s + 4 * quad]);
    A[s] = *reinterpret_cast<s16x8*>(&u);
  }
  __builtin_amdgcn_wave_barrier();   // reads stay before next staging writes
}

// ---------------------------------------------------------------------------
// Dual encoder pass sharing one B-read stream: two input tiles -> two outputs.
// ---------------------------------------------------------------------------
__device__ __forceinline__ void enc_pair(
    float p0e, float q0e, float p1e, float q1e,
    unsigned* hrow, const uint4* Bf, const float* epi,
    float w100, float w101, float w110, float w111, float b10, float b11,
    int lane, int quad, int l15,
    float& P0v, float& Q0v, float& P1v, float& Q1v)
{
  s16x8 A0[4], A1[4];
  layer1_frags<false>(p0e, q0e, hrow, w100, w101, w110, w111, b10, b11,
                      lane, quad, l15, A0);
  layer1_frags<false>(p1e, q1e, hrow, w100, w101, w110, w111, b10, b11,
                      lane, quad, l15, A1);

  float sP0[4] = {0,0,0,0}, sQ0[4] = {0,0,0,0};
  float sP1[4] = {0,0,0,0}, sQ1[4] = {0,0,0,0};
#pragma unroll
  for (int t = 0; t < 8; t++) {
    float b2v = epi[16 * t + l15];               // pre-scaled b2
    f32x4 acc0 = {b2v, b2v, b2v, b2v};
    f32x4 acc1 = {b2v, b2v, b2v, b2v};
#pragma unroll
    for (int s = 0; s < 4; s++) {
      uint4 bu = Bf[(s * 8 + t) * 64 + lane];     // ONE read, TWO MFMAs
      s16x8 Bv = *reinterpret_cast<s16x8*>(&bu);
      acc0 = __builtin_amdgcn_mfma_f32_16x16x32_bf16(A0[s], Bv, acc0, 0, 0, 0);
      acc1 = __builtin_amdgcn_mfma_f32_16x16x32_bf16(A1[s], Bv, acc1, 0, 0, 0);
    }
    float w3Pv = epi[128 + 16 * t + l15];
    float w3Qv = epi[256 + 16 * t + l15];
#pragma unroll
    for (int r = 0; r < 4; r++) {
      float h0 = tanh_pre(acc0[r]);
      float h1 = tanh_pre(acc1[r]);
      sP0[r] = fmaf(h0, w3Pv, sP0[r]); sQ0[r] = fmaf(h0, w3Qv, sQ0[r]);
      sP1[r] = fmaf(h1, w3Pv, sP1[r]); sQ1[r] = fmaf(h1, w3Qv, sQ1[r]);
    }
  }
#pragma unroll
  for (int m = 1; m < 16; m <<= 1) {
#pragma unroll
    for (int r = 0; r < 4; r++) {
      sP0[r] += __shfl_xor(sP0[r], m, 64);
      sQ0[r] += __shfl_xor(sQ0[r], m, 64);
      sP1[r] += __shfl_xor(sP1[r], m, 64);
      sQ1[r] += __shfl_xor(sQ1[r], m, 64);
    }
  }
  P0v = (l15 == 0) ? sP0[0] : (l15 == 1) ? sP0[1] : (l15 == 2) ? sP0[2] : sP0[3];
  Q0v = (l15 == 0) ? sQ0[0] : (l15 == 1) ? sQ0[1] : (l15 == 2) ? sQ0[2] : sQ0[3];
  P1v = (l15 == 0) ? sP1[0] : (l15 == 1) ? sP1[1] : (l15 == 2) ? sP1[2] : sP1[3];
  Q1v = (l15 == 0) ? sQ1[0] : (l15 == 1) ? sQ1[1] : (l15 == 2) ? sQ1[2] : sQ1[3];
}

// ---------------------------------------------------------------------------
// Single (decoder) pass, SCAT inputs.
// ---------------------------------------------------------------------------
__device__ __forceinline__ void dec_pass(
    float pe, float qe, unsigned* hrow, const uint4* Bf, const float* epi,
    float w100, float w101, float w110, float w111, float b10, float b11,
    int lane, int quad, int l15, float& vP, float& vQ)
{
  s16x8 A[4];
  layer1_frags<true>(pe, qe, hrow, w100, w101, w110, w111, b10, b11,
                     lane, quad, l15, A);
  float sP[4] = {0,0,0,0}, sQ[4] = {0,0,0,0};
#pragma unroll
  for (int t = 0; t < 8; t++) {
    float b2v = epi[16 * t + l15];               // pre-scaled b2
    f32x4 acc = {b2v, b2v, b2v, b2v};
#pragma unroll
    for (int s = 0; s < 4; s++) {
      uint4 bu = Bf[(s * 8 + t) * 64 + lane];
      s16x8 Bv = *reinterpret_cast<s16x8*>(&bu);
      acc = __builtin_amdgcn_mfma_f32_16x16x32_bf16(A[s], Bv, acc, 0, 0, 0);
    }
    float w3Pv = epi[128 + 16 * t + l15];
    float w3Qv = epi[256 + 16 * t + l15];
#pragma unroll
    for (int r = 0; r < 4; r++) {
      float h = tanh_pre(acc[r]);
      sP[r] = fmaf(h, w3Pv, sP[r]);
      sQ[r] = fmaf(h, w3Qv, sQ[r]);
    }
  }
#pragma unroll
  for (int m = 1; m < 16; m <<= 1) {
#pragma unroll
    for (int r = 0; r < 4; r++) {
      sP[r] += __shfl_xor(sP[r], m, 64);
      sQ[r] += __shfl_xor(sQ[r], m, 64);
    }
  }
  vP = (l15 == 0) ? sP[0] : (l15 == 1) ? sP[1] : (l15 == 2) ? sP[2] : sP[3];
  vQ = (l15 == 0) ? sQ[0] : (l15 == 1) ? sQ[1] : (l15 == 2) ? sQ[2] : sQ[3];
}

// ---------------------------------------------------------------------------
// Main persistent kernel (R9 structure).
// ---------------------------------------------------------------------------
__global__ __launch_bounds__(1024, 1) void mlp_main(
    const float* __restrict__ p0, const float* __restrict__ q0,
    const float* __restrict__ p1, const float* __restrict__ q1,
    const float* __restrict__ eW1, const float* __restrict__ eb1,
    const float* __restrict__ eW2, const float* __restrict__ eb2,
    const float* __restrict__ eW3, const float* __restrict__ eb3,
    const float* __restrict__ dW1, const float* __restrict__ db1,
    const float* __restrict__ dW2, const float* __restrict__ db2,
    const float* __restrict__ dW3, const float* __restrict__ db3,
    const float* __restrict__ omega, const float* __restrict__ Pt,
    const float* __restrict__ Qt, const float* __restrict__ dtp,
    float* __restrict__ acc5, unsigned* __restrict__ counter,
    float* __restrict__ PQ, float* __restrict__ out, int n)
{
  __shared__ uint4 BfE[2048];               // 32 KB enc B-frags (pre-scaled)
  __shared__ uint4 BfD[2048];               // 32 KB dec B-frags (pre-scaled)
  __shared__ unsigned h1s[16][16 * 68 + 4]; // wave-private h1 staging (~70 KB)
  __shared__ float encEpi[384];             // enc K*b2 | W3P | W3Q
  __shared__ float decEpi[384];             // dec K*b2 | W3P | W3Q
  __shared__ float red[16][5];
  __shared__ unsigned lastflag;

  int tid = threadIdx.x;
  // self-swizzle: frag f=s*8+t; lane L holds B[k=32s+(L>>4)*8+j][col=16t+(L&15)]
  // W2 pre-scaled by K2LOG2E at pack time.
#pragma unroll
  for (int it = 0; it < 8; it++) {
    int id = tid + it * 1024;               // u32 entry 0..8191
    int jj = id & 3, ln = (id >> 2) & 63, f = id >> 8;
    int s = f >> 3, t = f & 7;
    int k   = 32 * s + 8 * (ln >> 4) + 2 * jj;
    int col = 16 * t + (ln & 15);
    ((unsigned*)BfE)[id] = pack2rne(eW2[k * 128 + col] * K2LOG2E,
                                    eW2[(k + 1) * 128 + col] * K2LOG2E);
    ((unsigned*)BfD)[id] = pack2rne(dW2[k * 128 + col] * K2LOG2E,
                                    dW2[(k + 1) * 128 + col] * K2LOG2E);
  }
  if (tid < 128) {
    encEpi[tid]       = eb2[tid] * K2LOG2E;
    encEpi[128 + tid] = eW3[2 * tid];
    encEpi[256 + tid] = eW3[2 * tid + 1];
  } else if (tid < 256) {
    int u = tid - 128;
    decEpi[u]       = db2[u] * K2LOG2E;
    decEpi[128 + u] = dW3[2 * u];
    decEpi[256 + u] = dW3[2 * u + 1];
  }

  int wave = tid >> 6, lane = tid & 63;
  int quad = lane >> 4, l15 = lane & 15;

  // layer-1 consts (lane owns hidden dims 2*lane, 2*lane+1), pre-scaled
  float ew100 = eW1[2 * lane] * K2LOG2E,       ew101 = eW1[2 * lane + 1] * K2LOG2E;
  float ew110 = eW1[128 + 2 * lane] * K2LOG2E, ew111 = eW1[128 + 2 * lane + 1] * K2LOG2E;
  float eb10 = eb1[2 * lane] * K2LOG2E, eb11 = eb1[2 * lane + 1] * K2LOG2E;
  float dw100 = dW1[2 * lane] * K2LOG2E,       dw101 = dW1[2 * lane + 1] * K2LOG2E;
  float dw110 = dW1[128 + 2 * lane] * K2LOG2E, dw111 = dW1[128 + 2 * lane + 1] * K2LOG2E;
  float db10 = db1[2 * lane] * K2LOG2E, db11 = db1[2 * lane + 1] * K2LOG2E;
  float eb3P = eb3[0], eb3Q = eb3[1];
  float db3P = db3[0], db3Q = db3[1];
  float dt = dtp[0];
  float s0 = 0.f, s1 = 0.f, s2 = 0.f, s3 = 0.f, s4 = 0.f;
  __syncthreads();   // LDS staging done; the only block barrier before tail

  int nwaves = gridDim.x * 16;
  int gwave  = blockIdx.x * 16 + wave;
  int ntiles = (n + 15) >> 4;
  unsigned* hrow = &h1s[wave][0];

  // ---- fused exact-fp32 symplectic rows: one per wave for gwave < 128 ----
  // (reads RAW weights from global; unaffected by pre-scaling)
  if (gwave < 128) {
    int r = gwave;
    int m = r & 31, c = r >> 5;           // c: 0=p+e 1=p-e 2=q+e 3=q-e
    float p = p0[m], q = q0[m];
    p += (c == 0) ? EPS_FD : (c == 1) ? -EPS_FD : 0.f;
    q += (c == 2) ? EPS_FD : (c == 3) ? -EPS_FD : 0.f;
    float* hf = (float*)hrow;             // wave-private LDS as fp32 h1[128]
    int t0 = 2 * lane, t1 = 2 * lane + 1;
    float h0 = tanhf(fmaf(p, eW1[t0], fmaf(q, eW1[128 + t0], eb1[t0])));
    float h1v = tanhf(fmaf(p, eW1[t1], fmaf(q, eW1[128 + t1], eb1[t1])));
    hf[t0] = h0; hf[t1] = h1v;
    __builtin_amdgcn_wave_barrier();
    float a0 = eb2[t0], a1 = eb2[t1];
#pragma unroll 8
    for (int k = 0; k < 128; k++) {
      float hk = hf[k];                   // LDS broadcast (same addr all lanes)
      a0 = fmaf(hk, eW2[k * 128 + t0], a0);
      a1 = fmaf(hk, eW2[k * 128 + t1], a1);
    }
    float g0 = tanhf(a0), g1 = tanhf(a1);
    float cP = fmaf(g0, eW3[2 * t0],     g1 * eW3[2 * t1]);
    float cQ = fmaf(g0, eW3[2 * t0 + 1], g1 * eW3[2 * t1 + 1]);
#pragma unroll
    for (int mm = 1; mm < 64; mm <<= 1) {
      cP += __shfl_xor(cP, mm, 64);
      cQ += __shfl_xor(cQ, mm, 64);
    }
    if (lane == 0) {
      atomicExch(&PQ[2 * r],     cP + eb3P);   // device-scope publish
      atomicExch(&PQ[2 * r + 1], cQ + eb3Q);
    }
    __builtin_amdgcn_wave_barrier();      // hf reads done before tile reuse
  }

  for (int tile = gwave; tile < ntiles; tile += nwaves) {
    int base = tile * 16;
    int e = base + l15; if (e >= n) e = n - 1;
    float p0e = p0[e], q0e = q0[e];
    float p1e = p1[e], q1e = q1[e];
    // hoisted loss loads at the scattered output index
    int o = base + quad * 4 + l15;                 // valid where l15<4
    int o16 = base + quad * 4 + (l15 & 3);
    if (o16 >= n) o16 = n - 1;
    float Lom = omega[o16], LPt = Pt[o16], LQt = Qt[o16];
    float Lp0 = p0[o16],    Lq0 = q0[o16];

    float P0v, Q0v, P1v, Q1v, RPv, RQv;
    enc_pair(p0e, q0e, p1e, q1e, hrow, BfE, encEpi,
             ew100, ew101, ew110, ew111, eb10, eb11,
             lane, quad, l15, P0v, Q0v, P1v, Q1v);
    P0v += eb3P; Q0v += eb3Q;
    P1v += eb3P; Q1v += eb3Q;
    // dec input: enc outputs on scattered owner lanes 16*(ee>>2)+(ee&3)
    dec_pass(P0v, Q0v, hrow, BfD, decEpi,
             dw100, dw101, dw110, dw111, db10, db11,
             lane, quad, l15, RPv, RQv);
    RPv += db3P; RQv += db3Q;

    if (l15 < 4 && o < n) {
      float dp = Lp0 - RPv, dq = Lq0 - RQv;
      s0 += dp * dp + dq * dq;                       // recon
      float d1 = P0v - P1v; s1 += d1 * d1;           // conservation
      s2 += 1.0f - cos_fast(Q1v - Q0v - Lom * dt);   // evolution
      float g = P0v - LPt; s3 += g * g;              // gauge P
      s4 += 1.0f - cos_fast(Q0v - LQt);              // gauge Q
    }
  }

  // block reduction -> global atomics -> ticket -> last block finalizes
#pragma unroll
  for (int m = 1; m < 64; m <<= 1) {
    s0 += __shfl_xor(s0, m, 64);
    s1 += __shfl_xor(s1, m, 64);
    s2 += __shfl_xor(s2, m, 64);
    s3 += __shfl_xor(s3, m, 64);
    s4 += __shfl_xor(s4, m, 64);
  }
  if (lane == 0) {
    red[wave][0] = s0; red[wave][1] = s1; red[wave][2] = s2;
    red[wave][3] = s3; red[wave][4] = s4;
  }
  __syncthreads();
  if (tid == 0) {
#pragma unroll
    for (int i = 0; i < 5; i++) {
      float v = 0.f;
#pragma unroll
      for (int w = 0; w < 16; w++) v += red[w][i];
      atomicAdd(&acc5[i], v);
    }
    __threadfence();
    unsigned prev = atomicAdd(counter, 1u);
    lastflag = (prev == gridDim.x - 1) ? 1u : 0u;
  }
  __syncthreads();
  if (lastflag) {
    __threadfence();
    if (tid < 64) {
      float v = 0.f;
      if (tid < 32) {
        // PQ read through device-scope atomics (cross-XCD safe)
        float Ppp = atomicAdd(&PQ[2 * tid], 0.f);
        float Qpp = atomicAdd(&PQ[2 * tid + 1], 0.f);
        float Ppm = atomicAdd(&PQ[2 * (32 + tid)], 0.f);
        float Qpm = atomicAdd(&PQ[2 * (32 + tid) + 1], 0.f);
        float Pqp = atomicAdd(&PQ[2 * (64 + tid)], 0.f);
        float Qqp = atomicAdd(&PQ[2 * (64 + tid) + 1], 0.f);
        float Pqm = atomicAdd(&PQ[2 * (96 + tid)], 0.f);
        float Qqm = atomicAdd(&PQ[2 * (96 + tid) + 1], 0.f);
        float inv2e = 1.0f / (2.0f * EPS_FD);
        float dPdp = (Ppp - Ppm) * inv2e, dPdq = (Pqp - Pqm) * inv2e;
        float dQdp = (Qpp - Qpm) * inv2e, dQdq = (Qqp - Qqm) * inv2e;
        float pb = dPdq * dQdp - dPdp * dQdq;
        float d = fabsf(pb) - 1.0f;
        v = d * d;
      }
#pragma unroll
      for (int m = 1; m < 64; m <<= 1) v += __shfl_xor(v, m, 64);
      if (tid == 0) {
        float inv_n = 1.0f / (float)n;
        float recon = atomicAdd(&acc5[0], 0.f) * inv_n;
        float cons  = atomicAdd(&acc5[1], 0.f) * inv_n;
        float evo   = atomicAdd(&acc5[2], 0.f) * inv_n;
        float gauge = (atomicAdd(&acc5[3], 0.f) + atomicAdd(&acc5[4], 0.f)) * inv_n;
        float symp  = v * (1.0f / 32.0f);
        float total = recon + 10.0f * cons + 5.0f * evo + 0.1f * symp + 5.0f * gauge;
        out[0] = total; out[1] = recon; out[2] = cons;
        out[3] = evo;   out[4] = symp;  out[5] = gauge;
      }
    }
  }
}

extern "C" void kernel_launch(void* const* d_in, const int* in_sizes, int n_in,
                              void* d_out, int out_size, void* d_ws, size_t ws_size,
                              hipStream_t stream)
{
  const float* p0    = (const float*)d_in[0];
  const float* q0    = (const float*)d_in[1];
  const float* p1    = (const float*)d_in[2];
  const float* q1    = (const float*)d_in[3];
  const float* omega = (const float*)d_in[4];
  const float* dtp   = (const float*)d_in[5];
  const float* Pt    = (const float*)d_in[6];
  const float* Qt    = (const float*)d_in[7];
  const float* encW1 = (const float*)d_in[8];
  const float* encb1 = (const float*)d_in[9];
  const float* encW2 = (const float*)d_in[10];
  const float* encb2 = (const float*)d_in[11];
  const float* encW3 = (const float*)d_in[12];
  const float* encb3 = (const float*)d_in[13];
  const float* decW1 = (const float*)d_in[14];
  const float* decb1 = (const float*)d_in[15];
  const float* decW2 = (const float*)d_in[16];
  const float* decb2 = (const float*)d_in[17];
  const float* decW3 = (const float*)d_in[18];
  const float* decb3 = (const float*)d_in[19];

  int n = in_sizes[0];
  float* acc5 = (float*)d_ws;                  // 5 loss accumulators
  unsigned* counter = (unsigned*)(acc5 + 8);   // ticket
  float* PQ = (float*)(acc5 + 16);             // 256 floats (symp encodes)

  hipMemsetAsync(acc5, 0, 64, stream);         // acc5 + counter

  mlp_main<<<NBLK, 1024, 0, stream>>>(
      p0, q0, p1, q1,
      encW1, encb1, encW2, encb2, encW3, encb3,
      decW1, decb1, decW2, decb2, decW3, decb3,
      omega, Pt, Qt, dtp, acc5, counter, PQ, (float*)d_out, n);
}